// Round 5
// baseline (90.915 us; speedup 1.0000x reference)
//
#include <hip/hip_runtime.h>
#include <math.h>

#define LN_EPS 1e-6f

// ---------------------------------------------------------------------------
// Setup: compute the 31 batch-invariant scalars on one thread.
//   ws[0..8]   = M1 (row-major 3x3)
//   ws[9..17]  = M2
//   ws[18..26] = A   (folded linear term)
//   ws[27..29] = c0  (folded constant term)
//   ws[30]     = S_aa (coefficient of cross(M1 x, M2 x))
// ---------------------------------------------------------------------------

__device__ inline void compute_M(const float* wl /*[3][20]*/, const float* wd /*[3][3]*/,
                                 const float Rm[20][3], float M[3][3]) {
    // y = ln_linear(wl, Rm): y[g][k] = sum_f wl[g][f] * Rm[f][k]
    float y[3][3];
    for (int g = 0; g < 3; ++g)
        for (int k = 0; k < 3; ++k) {
            float s = 0.f;
            for (int f = 0; f < 20; ++f) s += wl[g * 20 + f] * Rm[f][k];
            y[g][k] = s;
        }
    // d = ln_linear(wd, y)
    float d[3][3];
    for (int g = 0; g < 3; ++g)
        for (int k = 0; k < 3; ++k) {
            float s = 0.f;
            for (int f = 0; f < 3; ++f) s += wd[g * 3 + f] * y[f][k];
            d[g][k] = s;
        }
    // LN Killing ReLU (per feature row f)
    float mm[3][3];
    for (int f = 0; f < 3; ++f) {
        float kf = -2.f * (y[f][0] * d[f][0] + y[f][1] * d[f][1] + y[f][2] * d[f][2]);
        float dd = -2.f * (d[f][0] * d[f][0] + d[f][1] * d[f][1] + d[f][2] * d[f][2]);
        float coef = kf / (dd + LN_EPS);
        for (int k = 0; k < 3; ++k)
            mm[f][k] = (kf < 0.f) ? y[f][k] : (y[f][k] - coef * d[f][k]);
    }
    // m1 = transpose(mm) -> [k][f]; M = m1 @ m1^T: M[k][l] = sum_f mm[f][k]*mm[f][l]
    for (int k = 0; k < 3; ++k)
        for (int l = 0; l < 3; ++l) {
            float s = 0.f;
            for (int f = 0; f < 3; ++f) s += mm[f][k] * mm[f][l];
            M[k][l] = s;
        }
}

__global__ void setup_kernel(const float* __restrict__ t, const float* __restrict__ R,
                             const float* __restrict__ m, const float* __restrict__ w1l,
                             const float* __restrict__ w1d, const float* __restrict__ w2l,
                             const float* __restrict__ w2d, const float* __restrict__ wb,
                             const float* __restrict__ wo, float* __restrict__ ws) {
    if (threadIdx.x != 0 || blockIdx.x != 0) return;

    const float tt = t[0];
    const float st = sinf(tt), ct = cosf(tt);
    const float uv[3] = {10.f * st, 10.f * ct, 10.f * st};
    float u[3];
    for (int i = 0; i < 3; ++i)
        u[i] = R[i * 3 + 0] * uv[0] + R[i * 3 + 1] * uv[1] + R[i * 3 + 2] * uv[2];

    // Rm[f][k] = (R @ m)[k][f] = sum_j R[k][j] * m[j][f]
    float Rm[20][3];
    for (int f = 0; f < 20; ++f)
        for (int k = 0; k < 3; ++k) {
            float s = 0.f;
            for (int j = 0; j < 3; ++j) s += R[k * 3 + j] * m[j * 20 + f];
            Rm[f][k] = s;
        }

    float M1[3][3], M2[3][3];
    compute_M(w1l, w1d, Rm, M1);
    compute_M(w2l, w2d, Rm, M2);

    // v1 = M1 u, v2 = M2 u
    float v1[3], v2[3];
    for (int k = 0; k < 3; ++k) {
        v1[k] = M1[k][0] * u[0] + M1[k][1] * u[1] + M1[k][2] * u[2];
        v2[k] = M2[k][0] * u[0] + M2[k][1] * u[1] + M2[k][2] * u[2];
    }

    // weight-contraction scalars over the 20 features
    float Sa = 0.f, Sb = 0.f, Saa = 0.f, Sab = 0.f, Sbb = 0.f;
    for (int g = 0; g < 20; ++g) {
        float a = wb[g * 2 + 0], b = wb[g * 2 + 1], w = wo[g];
        Sa += w * a; Sb += w * b;
        Saa += w * a * a; Sab += w * a * b; Sbb += w * b * b;
    }

    // hat(v)[i][j]: [[0,-v2,v1],[v2,0,-v0],[-v1,v0,0]]
    auto hat = [](const float v[3], float H[3][3]) {
        H[0][0] = 0.f;    H[0][1] = -v[2]; H[0][2] = v[1];
        H[1][0] = v[2];   H[1][1] = 0.f;   H[1][2] = -v[0];
        H[2][0] = -v[1];  H[2][1] = v[0];  H[2][2] = 0.f;
    };
    float H1[3][3], H2[3][3];
    hat(v1, H1);  // hat(M1 u)
    hat(v2, H2);  // hat(M2 u)

    // A = Sab * ( -hat(v2) @ M1 + hat(v1) @ M2 ) + Sa * I
    float A[3][3];
    for (int i = 0; i < 3; ++i)
        for (int j = 0; j < 3; ++j) {
            float s = 0.f;
            for (int k = 0; k < 3; ++k)
                s += -H2[i][k] * M1[k][j] + H1[i][k] * M2[k][j];
            A[i][j] = Sab * s + ((i == j) ? Sa : 0.f);
        }

    // c0 = Sbb * (v1 x v2) + Sb * u
    float cr[3] = {v1[1] * v2[2] - v1[2] * v2[1],
                   v1[2] * v2[0] - v1[0] * v2[2],
                   v1[0] * v2[1] - v1[1] * v2[0]};
    float c0[3];
    for (int k = 0; k < 3; ++k) c0[k] = Sbb * cr[k] + Sb * u[k];

    for (int i = 0; i < 9; ++i) ws[i] = M1[i / 3][i % 3];
    for (int i = 0; i < 9; ++i) ws[9 + i] = M2[i / 3][i % 3];
    for (int i = 0; i < 9; ++i) ws[18 + i] = A[i / 3][i % 3];
    for (int k = 0; k < 3; ++k) ws[27 + k] = c0[k];
    ws[30] = Saa;
}

// ---------------------------------------------------------------------------
// Main streaming kernel: out = Saa*(M1 x cross M2 x) + A x + c0
// 4 points per thread via 3x float4 loads/stores (fully coalesced).
// ---------------------------------------------------------------------------

__device__ inline void point_op(const float* c, float X, float Y, float Z,
                                float& o0, float& o1, float& o2) {
    float p0 = c[0] * X + c[1] * Y + c[2] * Z;
    float p1 = c[3] * X + c[4] * Y + c[5] * Z;
    float p2 = c[6] * X + c[7] * Y + c[8] * Z;
    float q0 = c[9] * X + c[10] * Y + c[11] * Z;
    float q1 = c[12] * X + c[13] * Y + c[14] * Z;
    float q2 = c[15] * X + c[16] * Y + c[17] * Z;
    float cr0 = p1 * q2 - p2 * q1;
    float cr1 = p2 * q0 - p0 * q2;
    float cr2 = p0 * q1 - p1 * q0;
    float S = c[30];
    o0 = S * cr0 + c[18] * X + c[19] * Y + c[20] * Z + c[27];
    o1 = S * cr1 + c[21] * X + c[22] * Y + c[23] * Z + c[28];
    o2 = S * cr2 + c[24] * X + c[25] * Y + c[26] * Z + c[29];
}

__global__ __launch_bounds__(256) void main_kernel(const float* __restrict__ x,
                                                   float* __restrict__ out,
                                                   const float* __restrict__ ws,
                                                   int n4, int tail) {
    __shared__ float c[31];
    if (threadIdx.x < 31) c[threadIdx.x] = ws[threadIdx.x];
    __syncthreads();

    int tid = blockIdx.x * blockDim.x + threadIdx.x;

    if (tid < n4) {
        const float4* xin = (const float4*)x;
        float4 a = xin[tid * 3 + 0];
        float4 b = xin[tid * 3 + 1];
        float4 d = xin[tid * 3 + 2];
        float xs[12] = {a.x, a.y, a.z, a.w, b.x, b.y, b.z, b.w, d.x, d.y, d.z, d.w};
        float os[12];
#pragma unroll
        for (int p = 0; p < 4; ++p)
            point_op(c, xs[p * 3 + 0], xs[p * 3 + 1], xs[p * 3 + 2],
                     os[p * 3 + 0], os[p * 3 + 1], os[p * 3 + 2]);
        float4* op = (float4*)out;
        op[tid * 3 + 0] = make_float4(os[0], os[1], os[2], os[3]);
        op[tid * 3 + 1] = make_float4(os[4], os[5], os[6], os[7]);
        op[tid * 3 + 2] = make_float4(os[8], os[9], os[10], os[11]);
    } else if (tid == n4 && tail > 0) {
        // scalar tail (B % 4 leftover points)
        for (int p = 0; p < tail; ++p) {
            int idx = n4 * 4 + p;
            float o0, o1, o2;
            point_op(c, x[idx * 3 + 0], x[idx * 3 + 1], x[idx * 3 + 2], o0, o1, o2);
            out[idx * 3 + 0] = o0;
            out[idx * 3 + 1] = o1;
            out[idx * 3 + 2] = o2;
        }
    }
}

extern "C" void kernel_launch(void* const* d_in, const int* in_sizes, int n_in,
                              void* d_out, int out_size, void* d_ws, size_t ws_size,
                              hipStream_t stream) {
    const float* x   = (const float*)d_in[0];
    const float* t   = (const float*)d_in[1];
    const float* R   = (const float*)d_in[2];
    const float* m   = (const float*)d_in[3];
    const float* w1l = (const float*)d_in[4];
    const float* w1d = (const float*)d_in[5];
    const float* w2l = (const float*)d_in[6];
    const float* w2d = (const float*)d_in[7];
    const float* wb  = (const float*)d_in[8];
    const float* wo  = (const float*)d_in[9];
    float* out = (float*)d_out;
    float* ws  = (float*)d_ws;

    const int B = in_sizes[0] / 3;
    const int n4 = B / 4;
    const int tail = B % 4;

    setup_kernel<<<1, 64, 0, stream>>>(t, R, m, w1l, w1d, w2l, w2d, wb, wo, ws);

    const int nthreads = n4 + (tail ? 1 : 0);
    const int blocks = (nthreads + 255) / 256;
    main_kernel<<<blocks, 256, 0, stream>>>(x, out, ws, n4, tail);
}